// Round 4
// baseline (507.092 us; speedup 1.0000x reference)
//
#include <hip/hip_runtime.h>

typedef _Float16 f16x8 __attribute__((ext_vector_type(8)));
typedef float    f32x4 __attribute__((ext_vector_type(4)));

static constexpr int BATCH = 32;
static constexpr int CDIM  = 256;    // C
static constexpr int HW    = 4096;   // h (= A_H = K of GEMM1)
static constexpr int AW    = 1024;   // A rows (w)
static constexpr int AH    = 4096;   // A cols (h)
static constexpr int BW    = 256;    // B rows (c)
static constexpr int BH    = 512;    // B cols (d)
static constexpr int CHUNK = 4096;   // tie-rank chunk per block
static constexpr int NROWS = BATCH * CDIM;  // 8192 = N of merged GEMM1

// scratch u32 layout (relative to scratch base)
// [0..8319]      histA (p0:4096, p1:4096, p2:128)
// [8320..16639]  histB
// [16640..16647] selA   [16648..16655] selB
// [16656..16663] done (pass*2+y)
// [16664..16665] tieDone
// [16672..17695] tieCntA  [17696..18719] tieOffA
// [18720..18751] tieCntB  [18752..18783] tieOffB
static constexpr int SCRATCH_U32 = 18784;

__device__ __forceinline__ void gload16(const void* g, void* l) {
    __builtin_amdgcn_global_load_lds((const __attribute__((address_space(1))) void*)g,
                                     (__attribute__((address_space(3))) void*)l, 16, 0, 0);
}

// ---------------- fused hist pass + inline select (last-block ticket) ----------------
// PASS 0: bin = key>>19 (4096 bins);  PASS 1: filter key>>19==sel[0], bin=(key>>7)&4095;
// PASS 2: filter key>>7==(sel[0]<<12)|sel[2], bin = key&127.
template<int PASS>
__global__ void fused_hist_kernel(const float* __restrict__ sA, int nA, unsigned jA,
                                  const float* __restrict__ sB, int nB, unsigned jB,
                                  unsigned* __restrict__ scratch) {
    constexpr int BINS  = (PASS == 2) ? 128 : 4096;
    constexpr int SHIFT = (PASS == 0) ? 19 : (PASS == 1) ? 7 : 0;
    constexpr int PER   = (BINS + 255) / 256;
    __shared__ unsigned lh[4][BINS];
    __shared__ unsigned partial[256];
    __shared__ unsigned excl[256];
    __shared__ int islast;
    const int y = blockIdx.y;
    const float* s = y ? sB : sA;
    const int n = y ? nB : nA;
    const unsigned j = y ? jB : jA;
    unsigned* hist = scratch + (y ? 8320 : 0) + ((PASS == 0) ? 0 : (PASS == 1) ? 4096 : 8192);
    unsigned* sel  = scratch + 16640 + y * 8;
    unsigned* done = scratch + 16656 + PASS * 2 + y;
    const int t = threadIdx.x;
    const int wave = t >> 6;
    for (int i = t; i < 4 * BINS; i += 256) ((unsigned*)lh)[i] = 0;
    __syncthreads();
    unsigned mv = 0;
    if (PASS == 1) mv = sel[0];
    if (PASS == 2) mv = (sel[0] << 12) | sel[2];
    for (int i = blockIdx.x * 256 + t; i < n; i += gridDim.x * 256) {
        unsigned key = __float_as_uint(s[i]) & 0x7fffffffu;
        bool ok = (PASS == 0) || (PASS == 1 && (key >> 19) == mv) || (PASS == 2 && (key >> 7) == mv);
        if (ok) atomicAdd(&lh[wave][(key >> SHIFT) & (BINS - 1)], 1u);
    }
    __syncthreads();
    for (int b = t; b < BINS; b += 256) {
        unsigned v = lh[0][b] + lh[1][b] + lh[2][b] + lh[3][b];
        if (v) atomicAdd(&hist[b], v);
    }
    __threadfence();
    __syncthreads();
    if (t == 0) islast = (atomicAdd(done, 1u) == gridDim.x - 1);
    __syncthreads();
    if (!islast) return;
    // ---- inline select (atomic readback for device coherence) ----
    unsigned sum = 0;
    #pragma unroll
    for (int k = 0; k < PER; ++k) { int b = t * PER + k; if (b < BINS) sum += atomicAdd(&hist[b], 0u); }
    partial[t] = sum;
    __syncthreads();
    if (t == 0) { unsigned c = 0; for (int k = 0; k < 256; ++k) { excl[k] = c; c += partial[k]; } }
    __syncthreads();
    unsigned base = (PASS == 0) ? 0u : sel[(PASS == 1) ? 1 : 3];
    unsigned target = j - base;
    unsigned c = excl[t];
    if (target >= c && target < c + partial[t]) {
        #pragma unroll
        for (int k = 0; k < PER; ++k) {
            int b = t * PER + k;
            unsigned h = (b < BINS) ? atomicAdd(&hist[b], 0u) : 0;
            if (target < c + h) { sel[PASS * 2] = (unsigned)b; sel[PASS * 2 + 1] = base + c; break; }
            c += h;
        }
    }
}

// ---------------- fused tie count + scan ----------------
__global__ void fused_tie_kernel(const float* __restrict__ sA, int nA,
                                 const float* __restrict__ sB, int nB,
                                 unsigned* __restrict__ scratch) {
    __shared__ unsigned cnt;
    __shared__ int islast;
    __shared__ unsigned buf[256];
    const int y = blockIdx.y;
    const float* s = y ? sB : sA;
    const int n = y ? nB : nA;
    unsigned* sel    = scratch + 16640 + y * 8;
    unsigned* done   = scratch + 16664 + y;
    unsigned* tieCnt = y ? (scratch + 18720) : (scratch + 16672);
    unsigned* tieOff = y ? (scratch + 18752) : (scratch + 17696);
    const int nChunks = (n + CHUNK - 1) / CHUNK;
    const int t = threadIdx.x;
    const unsigned vcut = (sel[0] << 19) | (sel[2] << 7) | sel[4];
    int start = blockIdx.x * CHUNK;
    if (start < n) {
        if (t == 0) cnt = 0;
        __syncthreads();
        int end = min(n, start + CHUNK);
        unsigned local = 0;
        for (int i = start + t; i < end; i += 256)
            if ((__float_as_uint(s[i]) & 0x7fffffffu) == vcut) local++;
        if (local) atomicAdd(&cnt, local);
        __syncthreads();
        if (t == 0 && cnt) atomicAdd(&tieCnt[blockIdx.x], cnt);
    }
    __threadfence();
    __syncthreads();
    if (t == 0) islast = (atomicAdd(done, 1u) == gridDim.x - 1);
    __syncthreads();
    if (!islast) return;
    // ---- scan up to 1024 chunk counts with 256 threads x 4 ----
    unsigned c4[4];
    unsigned local = 0;
    #pragma unroll
    for (int k = 0; k < 4; ++k) {
        int idx = t * 4 + k;
        c4[k] = (idx < nChunks) ? atomicAdd(&tieCnt[idx], 0u) : 0;
        local += c4[k];
    }
    buf[t] = local;
    __syncthreads();
    for (int off = 1; off < 256; off <<= 1) {
        unsigned u = (t >= off) ? buf[t - off] : 0;
        __syncthreads();
        buf[t] += u;
        __syncthreads();
    }
    unsigned run = buf[t] - local;
    #pragma unroll
    for (int k = 0; k < 4; ++k) {
        int idx = t * 4 + k;
        if (idx < nChunks) { tieOff[idx] = run; run += c4[k]; }
    }
}

// ---------------- apply mask (+ fused f32 pass-through copy) ----------------
template<bool TR>
__global__ void apply_mask_kernel(const float* __restrict__ s, const float* __restrict__ w,
                                  int n, int rows, int cols,
                                  const unsigned* __restrict__ sel, unsigned j,
                                  const unsigned* __restrict__ tieOff,
                                  _Float16* __restrict__ out, float* __restrict__ wcopy) {
    const unsigned vcut = (sel[0] << 19) | (sel[2] << 7) | sel[4];
    const unsigned drop = j - sel[5];
    int start = blockIdx.x * CHUNK;
    int end = min(n, start + CHUNK);
    __shared__ unsigned segBase;
    __shared__ unsigned wcnt[4];
    if (threadIdx.x == 0) segBase = tieOff[blockIdx.x];
    __syncthreads();
    for (int base = start; base < end; base += (int)blockDim.x) {
        int i = base + (int)threadIdx.x;
        bool valid = i < end;
        unsigned bits = 0;
        if (valid) bits = __float_as_uint(s[i]) & 0x7fffffffu;
        bool tie = valid && (bits == vcut);
        unsigned long long m = __ballot(tie);
        int lane = threadIdx.x & 63;
        int wid  = threadIdx.x >> 6;
        if (lane == 0) wcnt[wid] = (unsigned)__popcll(m);
        unsigned lower = (unsigned)__popcll(m & ((1ull << lane) - 1ull));
        __syncthreads();
        unsigned wbase = 0, tot = 0;
        for (int q = 0; q < 4; ++q) { if (q < wid) wbase += wcnt[q]; tot += wcnt[q]; }
        unsigned myrank = segBase + wbase + lower;
        if (valid) {
            float wv = w[i];
            float mask;
            if (bits > vcut)      mask = 1.0f;
            else if (bits < vcut) mask = 0.0f;
            else                  mask = (myrank >= drop) ? 1.0f : 0.0f;
            float v = wv * mask;
            int oidx;
            if (TR) { int r = i / cols, c = i - r * cols; oidx = c * rows + r; }
            else    { oidx = i; }
            out[oidx] = (_Float16)v;
            wcopy[i] = wv;
        }
        __syncthreads();
        if (threadIdx.x == 0) segBase += tot;
        __syncthreads();
    }
}

// ---------------- GEMM1 (merged batch): temp[b][w][c] = sum_h Am[w][h] * x[(b,c)][h] ----------------
// Single GEMM M=1024 (w) x N=8192 (b,c) x K=4096. Both operands staged via global_load_lds
// with pre-swizzled global sources; x staged as raw f32, converted f32->f16 at fragment read.
// 128x128 tile, BK=64, 4 waves (2x2), 4x4 mfma_f32_16x16x32_f16 per wave. XCD-swizzled grid.
__global__ __launch_bounds__(256) void gemm1_kernel(
        const _Float16* __restrict__ Am,   // [1024][4096] f16
        const float* __restrict__ x,       // [8192][4096] f32  ((b,c) major)
        _Float16* __restrict__ temp) {     // [32][1024][256] f16
    __shared__ __align__(16) char lds[49152];
    char* As = lds;            // 16 KiB: 128 rows x 128B (f16), XOR-swz (row&7)<<4
    char* Xs = lds + 16384;    // 32 KiB: 128 rows x 256B (f32), XOR-swz (row&15)<<4
    const int t = threadIdx.x;
    const int lane = t & 63;
    const int wave = t >> 6;
    const int wm = (wave >> 1) * 64;
    const int wn = (wave & 1) * 64;

    // XCD-aware bijective swizzle of 512 blocks (512 % 8 == 0)
    const int wg = (blockIdx.x & 7) * 64 + (blockIdx.x >> 3);
    const int by = wg >> 6;    // M-tile 0..7   (w)
    const int bx = wg & 63;    // N-tile 0..63  (b,c)

    // A staging: 4 chunks/thread. row = i*32 + (t>>3), kkPhys = t&7, kkLog = kkPhys ^ (row&7)
    const int aRow = t >> 3;
    const int aKk  = (t & 7) ^ (aRow & 7);          // row&7 == (t>>3)&7 for i*32 steps
    const _Float16* aSrc = Am + ((size_t)by * 128 + aRow) * HW + aKk * 8;
    // X staging: 8 chunks/thread. row = i*16 + (t>>4), kkPhys = t&15, kkLog = kkPhys ^ (row&15)
    const int xRow = t >> 4;
    const int xKk  = (t & 15) ^ (xRow & 15);        // row&15 == (t>>4)&15 for i*16 steps
    const float* xSrc = x + ((size_t)bx * 128 + xRow) * HW + xKk * 4;

    f32x4 acc[4][4] = {};

    for (int kt = 0; kt < HW; kt += 64) {
        __syncthreads();
        #pragma unroll
        for (int i = 0; i < 4; ++i)
            gload16(aSrc + kt + (size_t)i * 32 * HW, As + i * 4096 + t * 16);
        #pragma unroll
        for (int i = 0; i < 8; ++i)
            gload16(xSrc + kt + (size_t)i * 16 * HW, Xs + i * 4096 + t * 16);
        __syncthreads();
        #pragma unroll
        for (int k2 = 0; k2 < 2; ++k2) {
            f16x8 af[4], bf[4];
            int kByteA = k2 * 64 + (lane >> 4) * 16;    // f16 tile
            int kByteX = k2 * 128 + (lane >> 4) * 32;   // f32 tile
            #pragma unroll
            for (int mi = 0; mi < 4; ++mi) {
                int row = wm + mi * 16 + (lane & 15);
                af[mi] = *(const f16x8*)(As + ((row * 128 + kByteA) ^ ((row & 7) << 4)));
            }
            #pragma unroll
            for (int ni = 0; ni < 4; ++ni) {
                int row = wn + ni * 16 + (lane & 15);
                f32x4 u0 = *(const f32x4*)(Xs + ((row * 256 + kByteX) ^ ((row & 15) << 4)));
                f32x4 u1 = *(const f32x4*)(Xs + ((row * 256 + kByteX + 16) ^ ((row & 15) << 4)));
                f16x8 h = { (_Float16)u0[0], (_Float16)u0[1], (_Float16)u0[2], (_Float16)u0[3],
                            (_Float16)u1[0], (_Float16)u1[1], (_Float16)u1[2], (_Float16)u1[3] };
                bf[ni] = h;
            }
            #pragma unroll
            for (int mi = 0; mi < 4; ++mi)
                #pragma unroll
                for (int ni = 0; ni < 4; ++ni)
                    acc[mi][ni] = __builtin_amdgcn_mfma_f32_16x16x32_f16(af[mi], bf[ni], acc[mi][ni], 0, 0, 0);
        }
    }

    // epilogue: D row (w) = by*128 + wm + (lane>>4)*4 + mi*16 + r ; col (b,c) = bx*128 + wn + ni*16 + (lane&15)
    int row0 = by * 128 + wm + ((lane >> 4) << 2);
    int col0 = bx * 128 + wn + (lane & 15);
    #pragma unroll
    for (int mi = 0; mi < 4; ++mi)
        #pragma unroll
        for (int ni = 0; ni < 4; ++ni)
            #pragma unroll
            for (int r = 0; r < 4; ++r) {
                int gw = row0 + mi * 16 + r;
                int gc = col0 + ni * 16;          // global (b,c)
                int b = gc >> 8, c = gc & 255;
                temp[(size_t)b * (AW * CDIM) + (size_t)gw * CDIM + c] = (_Float16)acc[mi][ni][r];
            }
}

// ---------------- GEMM2: out[b][w][d] = sum_c temp[b][w][c] * BmT[d][c] ----------------
__global__ __launch_bounds__(256) void gemm2_kernel(
        const _Float16* __restrict__ A, long aStride,
        const _Float16* __restrict__ B,
        float* __restrict__ outP, int M, int N, int K) {
    __shared__ __align__(16) char lds[32768];
    char* As = lds;
    char* Bs = lds + 16384;
    const int t = threadIdx.x;
    const int lane = t & 63;
    const int wave = t >> 6;
    const int wm = (wave >> 1) * 64;
    const int wn = (wave & 1) * 64;
    const int z = blockIdx.z;

    const int r0 = t >> 3;
    const int kk = t & 7;
    const int kkSwz = kk ^ (r0 & 7);

    const _Float16* aSrc = A + (size_t)z * aStride + ((size_t)blockIdx.y * 128 + r0) * K + kkSwz * 8;
    const _Float16* bSrc = B + ((size_t)blockIdx.x * 128 + r0) * K + kkSwz * 8;

    f32x4 acc[4][4] = {};

    for (int kt = 0; kt < K; kt += 64) {
        __syncthreads();
        #pragma unroll
        for (int i = 0; i < 4; ++i)
            gload16(aSrc + kt + (size_t)i * 32 * K, As + i * 4096 + t * 16);
        #pragma unroll
        for (int i = 0; i < 4; ++i)
            gload16(bSrc + kt + (size_t)i * 32 * K, Bs + i * 4096 + t * 16);
        __syncthreads();
        #pragma unroll
        for (int k2 = 0; k2 < 2; ++k2) {
            f16x8 af[4], bf[4];
            int kByte = k2 * 64 + (lane >> 4) * 16;
            #pragma unroll
            for (int mi = 0; mi < 4; ++mi) {
                int row = wm + mi * 16 + (lane & 15);
                af[mi] = *(const f16x8*)(As + ((row * 128 + kByte) ^ ((row & 7) << 4)));
            }
            #pragma unroll
            for (int ni = 0; ni < 4; ++ni) {
                int row = wn + ni * 16 + (lane & 15);
                bf[ni] = *(const f16x8*)(Bs + ((row * 128 + kByte) ^ ((row & 7) << 4)));
            }
            #pragma unroll
            for (int mi = 0; mi < 4; ++mi)
                #pragma unroll
                for (int ni = 0; ni < 4; ++ni)
                    acc[mi][ni] = __builtin_amdgcn_mfma_f32_16x16x32_f16(af[mi], bf[ni], acc[mi][ni], 0, 0, 0);
        }
    }

    int row0 = blockIdx.y * 128 + wm + ((lane >> 4) << 2);
    int col0 = blockIdx.x * 128 + wn + (lane & 15);
    size_t outBase = (size_t)z * M * N;
    #pragma unroll
    for (int mi = 0; mi < 4; ++mi)
        #pragma unroll
        for (int ni = 0; ni < 4; ++ni)
            #pragma unroll
            for (int r = 0; r < 4; ++r)
                outP[outBase + (size_t)(row0 + mi * 16 + r) * N + col0 + ni * 16] = acc[mi][ni][r];
}

// ---------------- launch ----------------
extern "C" void kernel_launch(void* const* d_in, const int* in_sizes, int n_in,
                              void* d_out, int out_size, void* d_ws, size_t ws_size,
                              hipStream_t stream) {
    const float* x     = (const float*)d_in[0];
    const float* A_ref = (const float*)d_in[1];
    const float* B_ref = (const float*)d_in[2];
    const float* sA    = (const float*)d_in[3];
    const float* sB    = (const float*)d_in[4];
    float* out = (float*)d_out;
    char* ws = (char*)d_ws;

    const int nA = AW * AH;  const unsigned jA = (unsigned)(nA / 2);
    const int nB = BW * BH;  const unsigned jB = (unsigned)(nB / 2);
    const int outElems = BATCH * AW * BH;  // 16,777,216 f32

    _Float16* Am     = (_Float16*)(ws + 0);          // [1024][4096] f16
    _Float16* BmT    = (_Float16*)(ws + 8388608);    // [512][256]  f16 (transposed masked B)
    _Float16* temp   = (_Float16*)(ws + 8650752);    // [32][1024][256] f16
    unsigned* scratch= (unsigned*)(ws + 25427968);
    unsigned* selA   = scratch + 16640;
    unsigned* selB   = scratch + 16648;
    unsigned* tieOffA= scratch + 17696;
    unsigned* tieOffB= scratch + 18752;

    // one memset for all selection scratch
    hipMemsetAsync(scratch, 0, SCRATCH_U32 * 4, stream);

    // ---- fused mask pipeline (A and B via blockIdx.y) ----
    fused_hist_kernel<0><<<dim3(256, 2), 256, 0, stream>>>(sA, nA, jA, sB, nB, jB, scratch);
    fused_hist_kernel<1><<<dim3(256, 2), 256, 0, stream>>>(sA, nA, jA, sB, nB, jB, scratch);
    fused_hist_kernel<2><<<dim3(256, 2), 256, 0, stream>>>(sA, nA, jA, sB, nB, jB, scratch);
    fused_tie_kernel<<<dim3(1024, 2), 256, 0, stream>>>(sA, nA, sB, nB, scratch);
    apply_mask_kernel<false><<<nA / CHUNK, 256, 0, stream>>>(sA, A_ref, nA, AW, AH, selA, jA, tieOffA, Am, out + outElems);
    apply_mask_kernel<true><<<nB / CHUNK, 256, 0, stream>>>(sB, B_ref, nB, BW, BH, selB, jB, tieOffB, BmT, out + outElems + nA);

    // ---- GEMM1 (merged batch, fused f32->f16 on x fragments) ----
    gemm1_kernel<<<512, 256, 0, stream>>>(Am, x, temp);

    // ---- GEMM2 ----
    gemm2_kernel<<<dim3(BH / 128, AW / 128, BATCH), 256, 0, stream>>>(
        temp, (long)AW * CDIM, BmT, out, AW, BH, CDIM);
}

// Round 5
// 212.678 us; speedup vs baseline: 2.3843x; 2.3843x over previous
//
#include <hip/hip_runtime.h>

typedef _Float16 f16x8 __attribute__((ext_vector_type(8)));
typedef _Float16 f16x4 __attribute__((ext_vector_type(4)));
typedef float    f32x4 __attribute__((ext_vector_type(4)));

static constexpr int BATCH = 32;
static constexpr int CDIM  = 256;    // C
static constexpr int HW    = 4096;   // h (= A_H = K of GEMM1)
static constexpr int AW    = 1024;   // A rows (w)
static constexpr int AH    = 4096;   // A cols (h)
static constexpr int BW    = 256;    // B rows (c)
static constexpr int BH    = 512;    // B cols (d)
static constexpr int CAND_CAP = 8192;

// scratch u32 layout
// 0     histA0[4096]   4096  histA1[4096]
// 8192  histB0[4096]   12288 histB1[4096]
// 16384 selA[8]  ([3]=target2 [4]=vcut [5]=cutIdx [6]=candCount)
// 16392 selB[8]
// 16400 candBitsA[8192]  24592 candIdxA[8192]
// 32784 candBitsB[8192]  40976 candIdxB[8192]
static constexpr int MEMSET_U32 = 16400;

__device__ __forceinline__ void gload16(const void* g, void* l) {
    __builtin_amdgcn_global_load_lds((const __attribute__((address_space(1))) void*)g,
                                     (__attribute__((address_space(3))) void*)l, 16, 0, 0);
}

// every block computes the same select result from a global 4096-bin histogram.
// res[0] = bin containing `target`, res[1] = count in earlier bins.
__device__ void select_bin_inline(const unsigned* __restrict__ hist, unsigned target,
                                  unsigned* shp /*[256]*/, unsigned* res /*[2]*/) {
    const int t = threadIdx.x;
    unsigned sum = 0;
    #pragma unroll
    for (int k = 0; k < 16; ++k) sum += hist[t * 16 + k];
    shp[t] = sum;
    __syncthreads();
    if (t == 0) {
        unsigned c = 0; int k = 0;
        while (c + shp[k] <= target) { c += shp[k]; ++k; }
        int b = k * 16;
        while (true) { unsigned h = hist[b]; if (target < c + h) break; c += h; ++b; }
        res[0] = (unsigned)b; res[1] = c;
    }
    __syncthreads();
}

// ---------------- pass 0: hist of key>>19 (12 bits), per-wave LDS hist ----------------
__global__ void hist0_kernel(const float* __restrict__ sA, int nA,
                             const float* __restrict__ sB, int nB,
                             unsigned* __restrict__ scratch) {
    __shared__ unsigned lh[4][4096];
    const int y = blockIdx.y;
    const float* s = y ? sB : sA;
    const int n4 = (y ? nB : nA) >> 2;
    unsigned* hist = scratch + (y ? 8192 : 0);
    const int t = threadIdx.x;
    const int wave = t >> 6;
    for (int i = t; i < 4 * 4096; i += 256) ((unsigned*)lh)[i] = 0;
    __syncthreads();
    for (int i = blockIdx.x * 256 + t; i < n4; i += gridDim.x * 256) {
        float4 v = reinterpret_cast<const float4*>(s)[i];
        atomicAdd(&lh[wave][(__float_as_uint(v.x) & 0x7fffffffu) >> 19], 1u);
        atomicAdd(&lh[wave][(__float_as_uint(v.y) & 0x7fffffffu) >> 19], 1u);
        atomicAdd(&lh[wave][(__float_as_uint(v.z) & 0x7fffffffu) >> 19], 1u);
        atomicAdd(&lh[wave][(__float_as_uint(v.w) & 0x7fffffffu) >> 19], 1u);
    }
    __syncthreads();
    for (int b = t; b < 4096; b += 256) {
        unsigned v = lh[0][b] + lh[1][b] + lh[2][b] + lh[3][b];
        if (v) atomicAdd(&hist[b], v);
    }
}

// ---------------- pass 1: inline select0, hist of (key>>7)&4095 among prefix matches ----------------
__global__ void hist1_kernel(const float* __restrict__ sA, int nA, unsigned jA,
                             const float* __restrict__ sB, int nB, unsigned jB,
                             unsigned* __restrict__ scratch) {
    __shared__ unsigned lh[4][4096];
    __shared__ unsigned shp[256];
    __shared__ unsigned res[2];
    const int y = blockIdx.y;
    const float* s = y ? sB : sA;
    const int n4 = (y ? nB : nA) >> 2;
    const unsigned j = y ? jB : jA;
    const unsigned* hist0 = scratch + (y ? 8192 : 0);
    unsigned* hist1 = scratch + 4096 + (y ? 8192 : 0);
    const int t = threadIdx.x;
    const int wave = t >> 6;
    for (int i = t; i < 4 * 4096; i += 256) ((unsigned*)lh)[i] = 0;
    select_bin_inline(hist0, j, shp, res);       // includes syncthreads
    const unsigned bin0 = res[0];
    for (int i = blockIdx.x * 256 + t; i < n4; i += gridDim.x * 256) {
        float4 v = reinterpret_cast<const float4*>(s)[i];
        unsigned k0 = __float_as_uint(v.x) & 0x7fffffffu;
        unsigned k1 = __float_as_uint(v.y) & 0x7fffffffu;
        unsigned k2 = __float_as_uint(v.z) & 0x7fffffffu;
        unsigned k3 = __float_as_uint(v.w) & 0x7fffffffu;
        if ((k0 >> 19) == bin0) atomicAdd(&lh[wave][(k0 >> 7) & 4095], 1u);
        if ((k1 >> 19) == bin0) atomicAdd(&lh[wave][(k1 >> 7) & 4095], 1u);
        if ((k2 >> 19) == bin0) atomicAdd(&lh[wave][(k2 >> 7) & 4095], 1u);
        if ((k3 >> 19) == bin0) atomicAdd(&lh[wave][(k3 >> 7) & 4095], 1u);
    }
    __syncthreads();
    for (int b = t; b < 4096; b += 256) {
        unsigned v = lh[0][b] + lh[1][b] + lh[2][b] + lh[3][b];
        if (v) atomicAdd(&hist1[b], v);
    }
}

// ---------------- extract: inline select0+select1, gather candidates with 24-bit prefix ----------------
__global__ void extract_kernel(const float* __restrict__ sA, int nA, unsigned jA,
                               const float* __restrict__ sB, int nB, unsigned jB,
                               unsigned* __restrict__ scratch) {
    __shared__ unsigned shp[256];
    __shared__ unsigned res0[2], res1[2];
    const int y = blockIdx.y;
    const float* s = y ? sB : sA;
    const int n4 = (y ? nB : nA) >> 2;
    const unsigned j = y ? jB : jA;
    const unsigned* hist0 = scratch + (y ? 8192 : 0);
    const unsigned* hist1 = scratch + 4096 + (y ? 8192 : 0);
    unsigned* sel = scratch + 16384 + y * 8;
    unsigned* candBits = scratch + (y ? 32784 : 16400);
    unsigned* candIdx  = candBits + CAND_CAP;
    const int t = threadIdx.x;
    select_bin_inline(hist0, j, shp, res0);
    select_bin_inline(hist1, j - res0[1], shp, res1);
    const unsigned pref = (res0[0] << 12) | res1[0];
    const unsigned base2 = res0[1] + res1[1];
    if (blockIdx.x == 0 && t == 0) sel[3] = j - base2;   // rank within candidate set
    for (int i = blockIdx.x * 256 + t; i < n4; i += gridDim.x * 256) {
        float4 v = reinterpret_cast<const float4*>(s)[i];
        #pragma unroll
        for (int k = 0; k < 4; ++k) {
            unsigned bits = __float_as_uint(k == 0 ? v.x : k == 1 ? v.y : k == 2 ? v.z : v.w) & 0x7fffffffu;
            if ((bits >> 7) == pref) {
                unsigned p = atomicAdd(&sel[6], 1u);
                if (p < CAND_CAP) { candBits[p] = bits; candIdx[p] = (unsigned)(i * 4 + k); }
            }
        }
    }
}

// ---------------- finalize: exact (value, index)-lexicographic rank among candidates ----------------
__global__ void finalize_kernel(unsigned* __restrict__ scratch) {
    __shared__ unsigned sb[CAND_CAP];
    __shared__ unsigned si[CAND_CAP];
    const int y = blockIdx.y;
    unsigned* sel = scratch + 16384 + y * 8;
    const unsigned* candBits = scratch + (y ? 32784 : 16400);
    const unsigned* candIdx  = candBits + CAND_CAP;
    const int t = threadIdx.x;
    unsigned cnt = sel[6]; if (cnt > CAND_CAP) cnt = CAND_CAP;
    const unsigned target = sel[3];
    for (unsigned c = t; c < cnt; c += 256) { sb[c] = candBits[c]; si[c] = candIdx[c]; }
    __syncthreads();
    for (unsigned c = t; c < cnt; c += 256) {
        unsigned b = sb[c], ix = si[c];
        unsigned r = 0;
        for (unsigned q = 0; q < cnt; ++q)
            r += (sb[q] < b) || (sb[q] == b && si[q] < ix);
        if (r == target) { sel[4] = b; sel[5] = ix; }
    }
}

// ---------------- apply: branchless mask + masked-f16 write + f32 pass-through copy ----------------
__global__ void apply_kernel(const float* __restrict__ sA, const float* __restrict__ wA,
                             _Float16* __restrict__ Am, float* __restrict__ wcopyA,
                             const float* __restrict__ sB, const float* __restrict__ wB,
                             _Float16* __restrict__ BmT, float* __restrict__ wcopyB,
                             int nA, int nB, const unsigned* __restrict__ scratch) {
    const int y = blockIdx.y;
    const float* s = y ? sB : sA;
    const float* w = y ? wB : wA;
    float* wcopy = y ? wcopyB : wcopyA;
    const int n4 = (y ? nB : nA) >> 2;
    const unsigned* sel = scratch + 16384 + y * 8;
    const unsigned vcut = sel[4], cutIdx = sel[5];
    const int t = threadIdx.x;
    for (int i = blockIdx.x * 256 + t; i < n4; i += gridDim.x * 256) {
        float4 sv = reinterpret_cast<const float4*>(s)[i];
        float4 wv = reinterpret_cast<const float4*>(w)[i];
        reinterpret_cast<float4*>(wcopy)[i] = wv;
        unsigned idx0 = (unsigned)i * 4;
        float m[4];
        #pragma unroll
        for (int k = 0; k < 4; ++k) {
            unsigned bits = __float_as_uint(k == 0 ? sv.x : k == 1 ? sv.y : k == 2 ? sv.z : sv.w) & 0x7fffffffu;
            bool keep = (bits > vcut) || (bits == vcut && (idx0 + k) >= cutIdx);
            m[k] = keep ? 1.0f : 0.0f;
        }
        if (!y) {
            f16x4 o = { (_Float16)(wv.x * m[0]), (_Float16)(wv.y * m[1]),
                        (_Float16)(wv.z * m[2]), (_Float16)(wv.w * m[3]) };
            *reinterpret_cast<f16x4*>(Am + idx0) = o;
        } else {
            int c = (int)(idx0 >> 9);           // row of B_ref [256][512]
            int d = (int)(idx0 & 511);
            BmT[(size_t)(d + 0) * BW + c] = (_Float16)(wv.x * m[0]);
            BmT[(size_t)(d + 1) * BW + c] = (_Float16)(wv.y * m[1]);
            BmT[(size_t)(d + 2) * BW + c] = (_Float16)(wv.z * m[2]);
            BmT[(size_t)(d + 3) * BW + c] = (_Float16)(wv.w * m[3]);
        }
    }
}

// ---------------- GEMM1 (merged batch): temp[b][w][c] = sum_h Am[w][h] * x[(b,c)][h] ----------------
// XCD-local x reuse: XCD k owns bx in [8k,8k+8); all 8 by for one bx run consecutively on that XCD,
// so each 2MB x-tile is fetched from HBM once and reused 8x out of that XCD's L2.
__global__ __launch_bounds__(256) void gemm1_kernel(
        const _Float16* __restrict__ Am,   // [1024][4096] f16
        const float* __restrict__ x,       // [8192][4096] f32  ((b,c) major)
        _Float16* __restrict__ temp) {     // [32][1024][256] f16
    __shared__ __align__(16) char lds[49152];
    char* As = lds;            // 16 KiB: 128 rows x 128B (f16), XOR-swz (row&7)<<4
    char* Xs = lds + 16384;    // 32 KiB: 128 rows x 256B (f32), XOR-swz (row&15)<<4
    const int t = threadIdx.x;
    const int lane = t & 63;
    const int wave = t >> 6;
    const int wm = (wave >> 1) * 64;
    const int wn = (wave & 1) * 64;

    const int xcd = blockIdx.x & 7;
    const int seq = blockIdx.x >> 3;
    const int bx = xcd * 8 + (seq >> 3);   // N-tile 0..63 (b,c)
    const int by = seq & 7;                // M-tile 0..7  (w)

    const int aRow = t >> 3;
    const int aKk  = (t & 7) ^ (aRow & 7);
    const _Float16* aSrc = Am + ((size_t)by * 128 + aRow) * HW + aKk * 8;
    const int xRow = t >> 4;
    const int xKk  = (t & 15) ^ (xRow & 15);
    const float* xSrc = x + ((size_t)bx * 128 + xRow) * HW + xKk * 4;

    f32x4 acc[4][4] = {};

    for (int kt = 0; kt < HW; kt += 64) {
        __syncthreads();
        #pragma unroll
        for (int i = 0; i < 4; ++i)
            gload16(aSrc + kt + (size_t)i * 32 * HW, As + i * 4096 + t * 16);
        #pragma unroll
        for (int i = 0; i < 8; ++i)
            gload16(xSrc + kt + (size_t)i * 16 * HW, Xs + i * 4096 + t * 16);
        __syncthreads();
        #pragma unroll
        for (int k2 = 0; k2 < 2; ++k2) {
            f16x8 af[4], bf[4];
            int kByteA = k2 * 64 + (lane >> 4) * 16;
            int kByteX = k2 * 128 + (lane >> 4) * 32;
            #pragma unroll
            for (int mi = 0; mi < 4; ++mi) {
                int row = wm + mi * 16 + (lane & 15);
                af[mi] = *(const f16x8*)(As + ((row * 128 + kByteA) ^ ((row & 7) << 4)));
            }
            #pragma unroll
            for (int ni = 0; ni < 4; ++ni) {
                int row = wn + ni * 16 + (lane & 15);
                f32x4 u0 = *(const f32x4*)(Xs + ((row * 256 + kByteX) ^ ((row & 15) << 4)));
                f32x4 u1 = *(const f32x4*)(Xs + ((row * 256 + kByteX + 16) ^ ((row & 15) << 4)));
                f16x8 h = { (_Float16)u0[0], (_Float16)u0[1], (_Float16)u0[2], (_Float16)u0[3],
                            (_Float16)u1[0], (_Float16)u1[1], (_Float16)u1[2], (_Float16)u1[3] };
                bf[ni] = h;
            }
            #pragma unroll
            for (int mi = 0; mi < 4; ++mi)
                #pragma unroll
                for (int ni = 0; ni < 4; ++ni)
                    acc[mi][ni] = __builtin_amdgcn_mfma_f32_16x16x32_f16(af[mi], bf[ni], acc[mi][ni], 0, 0, 0);
        }
    }

    int row0 = by * 128 + wm + ((lane >> 4) << 2);
    int col0 = bx * 128 + wn + (lane & 15);
    #pragma unroll
    for (int mi = 0; mi < 4; ++mi)
        #pragma unroll
        for (int ni = 0; ni < 4; ++ni)
            #pragma unroll
            for (int r = 0; r < 4; ++r) {
                int gw = row0 + mi * 16 + r;
                int gc = col0 + ni * 16;
                int b = gc >> 8, c = gc & 255;
                temp[(size_t)b * (AW * CDIM) + (size_t)gw * CDIM + c] = (_Float16)acc[mi][ni][r];
            }
}

// ---------------- GEMM2: out[b][w][d] = sum_c temp[b][w][c] * BmT[d][c] ----------------
__global__ __launch_bounds__(256) void gemm2_kernel(
        const _Float16* __restrict__ A, long aStride,
        const _Float16* __restrict__ B,
        float* __restrict__ outP, int M, int N, int K) {
    __shared__ __align__(16) char lds[32768];
    char* As = lds;
    char* Bs = lds + 16384;
    const int t = threadIdx.x;
    const int lane = t & 63;
    const int wave = t >> 6;
    const int wm = (wave >> 1) * 64;
    const int wn = (wave & 1) * 64;
    const int z = blockIdx.z;

    const int r0 = t >> 3;
    const int kk = t & 7;
    const int kkSwz = kk ^ (r0 & 7);

    const _Float16* aSrc = A + (size_t)z * aStride + ((size_t)blockIdx.y * 128 + r0) * K + kkSwz * 8;
    const _Float16* bSrc = B + ((size_t)blockIdx.x * 128 + r0) * K + kkSwz * 8;

    f32x4 acc[4][4] = {};

    for (int kt = 0; kt < K; kt += 64) {
        __syncthreads();
        #pragma unroll
        for (int i = 0; i < 4; ++i)
            gload16(aSrc + kt + (size_t)i * 32 * K, As + i * 4096 + t * 16);
        #pragma unroll
        for (int i = 0; i < 4; ++i)
            gload16(bSrc + kt + (size_t)i * 32 * K, Bs + i * 4096 + t * 16);
        __syncthreads();
        #pragma unroll
        for (int k2 = 0; k2 < 2; ++k2) {
            f16x8 af[4], bf[4];
            int kByte = k2 * 64 + (lane >> 4) * 16;
            #pragma unroll
            for (int mi = 0; mi < 4; ++mi) {
                int row = wm + mi * 16 + (lane & 15);
                af[mi] = *(const f16x8*)(As + ((row * 128 + kByte) ^ ((row & 7) << 4)));
            }
            #pragma unroll
            for (int ni = 0; ni < 4; ++ni) {
                int row = wn + ni * 16 + (lane & 15);
                bf[ni] = *(const f16x8*)(Bs + ((row * 128 + kByte) ^ ((row & 7) << 4)));
            }
            #pragma unroll
            for (int mi = 0; mi < 4; ++mi)
                #pragma unroll
                for (int ni = 0; ni < 4; ++ni)
                    acc[mi][ni] = __builtin_amdgcn_mfma_f32_16x16x32_f16(af[mi], bf[ni], acc[mi][ni], 0, 0, 0);
        }
    }

    int row0 = blockIdx.y * 128 + wm + ((lane >> 4) << 2);
    int col0 = blockIdx.x * 128 + wn + (lane & 15);
    size_t outBase = (size_t)z * M * N;
    #pragma unroll
    for (int mi = 0; mi < 4; ++mi)
        #pragma unroll
        for (int ni = 0; ni < 4; ++ni)
            #pragma unroll
            for (int r = 0; r < 4; ++r)
                outP[outBase + (size_t)(row0 + mi * 16 + r) * N + col0 + ni * 16] = acc[mi][ni][r];
}

// ---------------- launch ----------------
extern "C" void kernel_launch(void* const* d_in, const int* in_sizes, int n_in,
                              void* d_out, int out_size, void* d_ws, size_t ws_size,
                              hipStream_t stream) {
    const float* x     = (const float*)d_in[0];
    const float* A_ref = (const float*)d_in[1];
    const float* B_ref = (const float*)d_in[2];
    const float* sA    = (const float*)d_in[3];
    const float* sB    = (const float*)d_in[4];
    float* out = (float*)d_out;
    char* ws = (char*)d_ws;

    const int nA = AW * AH;  const unsigned jA = (unsigned)(nA / 2);
    const int nB = BW * BH;  const unsigned jB = (unsigned)(nB / 2);
    const int outElems = BATCH * AW * BH;  // 16,777,216 f32

    _Float16* Am     = (_Float16*)(ws + 0);          // [1024][4096] f16
    _Float16* BmT    = (_Float16*)(ws + 8388608);    // [512][256]  f16
    _Float16* temp   = (_Float16*)(ws + 8650752);    // [32][1024][256] f16
    unsigned* scratch= (unsigned*)(ws + 25427968);

    hipMemsetAsync(scratch, 0, MEMSET_U32 * 4, stream);

    // ---- mask pipeline (A and B halves via blockIdx.y) ----
    hist0_kernel<<<dim3(256, 2), 256, 0, stream>>>(sA, nA, sB, nB, scratch);
    hist1_kernel<<<dim3(256, 2), 256, 0, stream>>>(sA, nA, jA, sB, nB, jB, scratch);
    extract_kernel<<<dim3(256, 2), 256, 0, stream>>>(sA, nA, jA, sB, nB, jB, scratch);
    finalize_kernel<<<dim3(1, 2), 256, 0, stream>>>(scratch);
    apply_kernel<<<dim3(2048, 2), 256, 0, stream>>>(sA, A_ref, Am, out + outElems,
                                                    sB, B_ref, BmT, out + outElems + nA,
                                                    nA, nB, scratch);

    // ---- GEMM1 (merged batch, fused f32->f16 on x fragments, XCD-local x reuse) ----
    gemm1_kernel<<<512, 256, 0, stream>>>(Am, x, temp);

    // ---- GEMM2 ----
    gemm2_kernel<<<dim3(BH / 128, AW / 128, BATCH), 256, 0, stream>>>(
        temp, (long)AW * CDIM, BmT, out, AW, BH, CDIM);
}